// Round 18
// baseline (566.846 us; speedup 1.0000x reference)
//
#include <hip/hip_runtime.h>
#include <hip/hip_fp16.h>

#define M_CH 2
#define J_F 2000
#define I_F 2049
#define K_B 8
#define N_IT 5
#define NMF_EPS 1e-20f
#define IP_EPS 1e-20f

#define NB_TILE (65 * 63)
#define NB_INIT 128
#define CHJ 500   // j's per LDS-staged V chunk (16*500*4 = 32 KB)
#define NCH 4     // 4*500 = 2000

__device__ __forceinline__ float2 h2f(unsigned u) {
  __half2 h = *reinterpret_cast<__half2*>(&u);
  return __half22float2(h);
}
__device__ __forceinline__ float4 h4f(unsigned lo, unsigned hi) {
  float2 a = h2f(lo), b = h2f(hi);
  return make_float4(a.x, a.y, b.x, b.y);
}
__device__ __forceinline__ unsigned f2h(float a, float b) {
  __half2 h = __floats2half2_rn(a, b);
  return *reinterpret_cast<unsigned*>(&h);
}

// ===== single-pass setup: X -> Xhj + Xht (fp16); init T[n][i][8], V[n][k][j], W =====
template<int PK>
__global__ __launch_bounds__(256) void k_setup(const float2* __restrict__ X,
                                               const float* __restrict__ T0,
                                               const float* __restrict__ V0,
                                               float* __restrict__ T,
                                               float* __restrict__ V,
                                               float* __restrict__ W,
                                               __half* __restrict__ Xht,
                                               __half* __restrict__ Xhj) {
  int b = blockIdx.x;
  const int tid = threadIdx.x;
  if (b < NB_TILE) {
    if (!PK) return;
    __shared__ float4 Tl[32][33];
    const int i0 = (b % 65) * 32, j0 = (b / 65) * 32;
    const int la = tid & 31, su = tid >> 5;
#pragma unroll
    for (int p = 0; p < 4; ++p) {
      int jj = su + p * 8;
      int i = i0 + la, j = j0 + jj;
      if (i < I_F && j < J_F) {
        float2 a = X[(size_t)j * I_F + i];
        float2 c = X[(size_t)(J_F + j) * I_F + i];
        float4 x = make_float4(a.x, a.y, c.x, c.y);
        Tl[la][jj] = x;
        *(uint2*)(Xhj + ((size_t)j * I_F + i) * 4) =
            make_uint2(f2h(x.x, x.y), f2h(x.z, x.w));
      }
    }
    __syncthreads();
#pragma unroll
    for (int p = 0; p < 4; ++p) {
      int ii = su + p * 8;
      int i = i0 + ii, j = j0 + la;
      if (i < I_F && j < J_F) {
        float4 x = Tl[ii][la];
        *(uint2*)(Xht + ((size_t)i * J_F + j) * 4) =
            make_uint2(f2h(x.x, x.y), f2h(x.z, x.w));
      }
    }
    return;
  }
  b -= NB_TILE;
  int t = b * 256 + tid;
  const int stride = NB_INIT * 256;
  for (int idx = t; idx < 2 * I_F * K_B; idx += stride) {
    int n = idx / (I_F * K_B);
    int r = idx % (I_F * K_B);
    int i = r / K_B, k = r % K_B;
    T[idx] = T0[(i * K_B + k) * M_CH + n];
  }
  for (int idx = t; idx < 2 * K_B * J_F; idx += stride) {
    int n = idx / (K_B * J_F);
    int r = idx % (K_B * J_F);
    int k = r / J_F, j = r % J_F;
    V[idx] = V0[(k * J_F + j) * M_CH + n];
  }
  for (int i = t; i < I_F; i += stride) {
    W[i * 8 + 0] = 1.f; W[i * 8 + 1] = 0.f; W[i * 8 + 2] = 0.f; W[i * 8 + 3] = 0.f;
    W[i * 8 + 4] = 0.f; W[i * 8 + 5] = 0.f; W[i * 8 + 6] = 1.f; W[i * 8 + 7] = 0.f;
  }
}

// ---- cooperative V chunk stage: 16 rows x CHJ floats via float4 ----
__device__ __forceinline__ void stage_V(const float* __restrict__ V, int j0,
                                        float (*Vl)[CHJ], int tid) {
  for (int idx = tid; idx < 16 * (CHJ / 4); idx += 256) {
    int r = idx / (CHJ / 4), q = idx % (CHJ / 4);
    *(float4*)&Vl[r][q * 4] = *(const float4*)&V[(size_t)r * J_F + j0 + q * 4];
  }
}

// ==== T phase body: row i, chunked LDS-V, reduce, update T ====
template<int PK>
__device__ __forceinline__ void t_phase(const int i, const __half* __restrict__ Xht,
                                        const float2* __restrict__ X,
                                        const float4 w0, const float4 w1,
                                        float* __restrict__ T, const float* __restrict__ V,
                                        float (*Vl)[CHJ], float (*red)[32]) {
  const int tid = threadIdx.x;
  float tr0[K_B], tr1[K_B];
#pragma unroll
  for (int k = 0; k < K_B; ++k) {
    tr0[k] = T[(size_t)i * 8 + k];
    tr1[k] = T[((size_t)I_F + i) * 8 + k];
  }
  float num0[K_B] = {}, den0[K_B] = {}, num1[K_B] = {}, den1[K_B] = {};
  if (PK) {
    for (int c = 0; c < NCH; ++c) {
      __syncthreads();
      stage_V(V, c * CHJ, Vl, tid);
      __syncthreads();
      if (tid < CHJ / 2) {
        const int jj = tid * 2;
        const int j = c * CHJ + jj;
        uint4 raw = *(const uint4*)(Xht + ((size_t)i * J_F + j) * 4);
        float4 xa = h4f(raw.x, raw.y);
        float4 xb = h4f(raw.z, raw.w);
        float R0a = 0.f, R0b = 0.f, R1a = 0.f, R1b = 0.f;
#pragma unroll
        for (int k = 0; k < K_B; ++k) {
          R0a += tr0[k] * Vl[k][jj];     R0b += tr0[k] * Vl[k][jj + 1];
          R1a += tr1[k] * Vl[8 + k][jj]; R1b += tr1[k] * Vl[8 + k][jj + 1];
        }
        float yr, yi;
        yr = w0.x * xa.x - w0.y * xa.y + w0.z * xa.z - w0.w * xa.w;
        yi = w0.x * xa.y + w0.y * xa.x + w0.z * xa.w + w0.w * xa.z;
        float p0a = yr * yr + yi * yi;
        yr = w1.x * xa.x - w1.y * xa.y + w1.z * xa.z - w1.w * xa.w;
        yi = w1.x * xa.y + w1.y * xa.x + w1.z * xa.w + w1.w * xa.z;
        float p1a = yr * yr + yi * yi;
        yr = w0.x * xb.x - w0.y * xb.y + w0.z * xb.z - w0.w * xb.w;
        yi = w0.x * xb.y + w0.y * xb.x + w0.z * xb.w + w0.w * xb.z;
        float p0b = yr * yr + yi * yi;
        yr = w1.x * xb.x - w1.y * xb.y + w1.z * xb.z - w1.w * xb.w;
        yi = w1.x * xb.y + w1.y * xb.x + w1.z * xb.w + w1.w * xb.z;
        float p1b = yr * yr + yi * yi;
        float a0a = p0a / (R0a * R0a), b0a = 1.f / R0a;
        float a1a = p1a / (R1a * R1a), b1a = 1.f / R1a;
        float a0b = p0b / (R0b * R0b), b0b = 1.f / R0b;
        float a1b = p1b / (R1b * R1b), b1b = 1.f / R1b;
#pragma unroll
        for (int k = 0; k < K_B; ++k) {
          float va = Vl[k][jj], vb = Vl[k][jj + 1];
          float ua = Vl[8 + k][jj], ub = Vl[8 + k][jj + 1];
          num0[k] += a0a * va + a0b * vb;
          den0[k] += b0a * va + b0b * vb;
          num1[k] += a1a * ua + a1b * ub;
          den1[k] += b1a * ua + b1b * ub;
        }
      }
    }
    __syncthreads();
  } else {
    for (int j = tid; j < J_F; j += 256) {
      float2 a = X[(size_t)j * I_F + i];
      float2 c = X[(size_t)(J_F + j) * I_F + i];
      float4 x = make_float4(a.x, a.y, c.x, c.y);
      float yr = w0.x * x.x - w0.y * x.y + w0.z * x.z - w0.w * x.w;
      float yi = w0.x * x.y + w0.y * x.x + w0.z * x.w + w0.w * x.z;
      float p0 = yr * yr + yi * yi;
      float zr = w1.x * x.x - w1.y * x.y + w1.z * x.z - w1.w * x.w;
      float zi = w1.x * x.y + w1.y * x.x + w1.z * x.w + w1.w * x.z;
      float p1 = zr * zr + zi * zi;
      float v0[K_B], v1[K_B];
      float R0 = 0.f, R1 = 0.f;
#pragma unroll
      for (int k = 0; k < K_B; ++k) {
        v0[k] = V[(size_t)k * J_F + j];         R0 += tr0[k] * v0[k];
        v1[k] = V[(size_t)(K_B + k) * J_F + j]; R1 += tr1[k] * v1[k];
      }
      float a0 = p0 / (R0 * R0), b0 = 1.0f / R0;
      float a1 = p1 / (R1 * R1), b1 = 1.0f / R1;
#pragma unroll
      for (int k = 0; k < K_B; ++k) {
        num0[k] += a0 * v0[k]; den0[k] += b0 * v0[k];
        num1[k] += a1 * v1[k]; den1[k] += b1 * v1[k];
      }
    }
  }
  const int lane = tid & 63, wid = tid >> 6;
#pragma unroll
  for (int k = 0; k < K_B; ++k) {
    float a0 = num0[k], b0 = den0[k], a1 = num1[k], b1 = den1[k];
#pragma unroll
    for (int off = 32; off > 0; off >>= 1) {
      a0 += __shfl_xor(a0, off, 64);
      b0 += __shfl_xor(b0, off, 64);
      a1 += __shfl_xor(a1, off, 64);
      b1 += __shfl_xor(b1, off, 64);
    }
    if (lane == 0) {
      red[wid][k] = a0; red[wid][8 + k] = b0;
      red[wid][16 + k] = a1; red[wid][24 + k] = b1;
    }
  }
  __syncthreads();
  if (tid < 32) red[0][tid] = red[0][tid] + red[1][tid] + red[2][tid] + red[3][tid];
  __syncthreads();
  if (tid < 16) {
    int n = tid >> 3, k = tid & 7;
    float nu = red[0][n * 16 + k];
    float de = red[0][n * 16 + 8 + k];
    size_t idx = ((size_t)n * I_F + i) * 8 + k;
    float told = T[idx];
    T[idx] = fmaxf(told * sqrtf(nu / de), NMF_EPS);
  }
  __syncthreads();
}

// ==== D phase body: row i, chunked LDS-V, reduce 8 sums, thread0 solves ====
template<int PK>
__device__ __forceinline__ void d_phase(const int i, const __half* __restrict__ Xht,
                                        const float2* __restrict__ X,
                                        const float* __restrict__ T,
                                        const float* __restrict__ V,
                                        float* __restrict__ W,
                                        float (*Vl)[CHJ], float (*red)[32], float* wrow) {
  const int tid = threadIdx.x;
  float tr0[K_B], tr1[K_B];
#pragma unroll
  for (int k = 0; k < K_B; ++k) {
    tr0[k] = T[(size_t)i * K_B + k];
    tr1[k] = T[((size_t)I_F + i) * K_B + k];
  }
  float acc[8] = {};
  if (PK) {
    for (int c = 0; c < NCH; ++c) {
      __syncthreads();
      stage_V(V, c * CHJ, Vl, tid);
      __syncthreads();
      if (tid < CHJ / 2) {
        const int jj = tid * 2;
        const int j = c * CHJ + jj;
        uint4 raw = *(const uint4*)(Xht + ((size_t)i * J_F + j) * 4);
        float4 xa = h4f(raw.x, raw.y);
        float4 xb = h4f(raw.z, raw.w);
        float R0a = 0.f, R0b = 0.f, R1a = 0.f, R1b = 0.f;
#pragma unroll
        for (int k = 0; k < K_B; ++k) {
          R0a += tr0[k] * Vl[k][jj];     R0b += tr0[k] * Vl[k][jj + 1];
          R1a += tr1[k] * Vl[8 + k][jj]; R1b += tr1[k] * Vl[8 + k][jj + 1];
        }
        float wv0a = 1.0f / (R0a + IP_EPS), wv0b = 1.0f / (R0b + IP_EPS);
        float wv1a = 1.0f / (R1a + IP_EPS), wv1b = 1.0f / (R1b + IP_EPS);
        float p00a = xa.x * xa.x + xa.y * xa.y, p00b = xb.x * xb.x + xb.y * xb.y;
        float p11a = xa.z * xa.z + xa.w * xa.w, p11b = xb.z * xb.z + xb.w * xb.w;
        float pra = xa.x * xa.z + xa.y * xa.w, prb = xb.x * xb.z + xb.y * xb.w;
        float pia = xa.y * xa.z - xa.x * xa.w, pib = xb.y * xb.z - xb.x * xb.w;
        acc[0] += wv0a * p00a + wv0b * p00b;
        acc[1] += wv0a * p11a + wv0b * p11b;
        acc[2] += wv0a * pra + wv0b * prb;
        acc[3] += wv0a * pia + wv0b * pib;
        acc[4] += wv1a * p00a + wv1b * p00b;
        acc[5] += wv1a * p11a + wv1b * p11b;
        acc[6] += wv1a * pra + wv1b * prb;
        acc[7] += wv1a * pia + wv1b * pib;
      }
    }
    __syncthreads();
  } else {
    for (int j = tid; j < J_F; j += 256) {
      float2 a = X[(size_t)j * I_F + i];
      float2 c = X[(size_t)(J_F + j) * I_F + i];
      float4 x = make_float4(a.x, a.y, c.x, c.y);
      float R0 = 0.f, R1 = 0.f;
#pragma unroll
      for (int k = 0; k < K_B; ++k) {
        R0 += tr0[k] * V[(size_t)k * J_F + j];
        R1 += tr1[k] * V[(size_t)(K_B + k) * J_F + j];
      }
      float wv0 = 1.0f / (R0 + IP_EPS);
      float wv1 = 1.0f / (R1 + IP_EPS);
      float p00 = x.x * x.x + x.y * x.y;
      float p11 = x.z * x.z + x.w * x.w;
      float pr = x.x * x.z + x.y * x.w;
      float pi = x.y * x.z - x.x * x.w;
      acc[0] += wv0 * p00; acc[1] += wv0 * p11; acc[2] += wv0 * pr; acc[3] += wv0 * pi;
      acc[4] += wv1 * p00; acc[5] += wv1 * p11; acc[6] += wv1 * pr; acc[7] += wv1 * pi;
    }
  }
  const int lane = tid & 63, wid = tid >> 6;
#pragma unroll
  for (int v = 0; v < 8; ++v) {
    float a = acc[v];
#pragma unroll
    for (int off = 32; off > 0; off >>= 1) a += __shfl_xor(a, off, 64);
    if (lane == 0) red[wid][v] = a;
  }
  __syncthreads();
  if (tid < 8) red[0][tid] = red[0][tid] + red[1][tid] + red[2][tid] + red[3][tid];
  __syncthreads();
  if (tid == 0) {
    float4 wa = ((const float4*)W)[i * 2];
    float4 wb = ((const float4*)W)[i * 2 + 1];
    float w00r = wa.x, w00i = wa.y, w01r = wa.z, w01i = wa.w;
    float w10r = wb.x, w10i = wb.y, w11r = wb.z, w11i = wb.w;
    const float invJ = 1.0f / (float)J_F;
#pragma unroll
    for (int n = 0; n < 2; ++n) {
      float d00 = red[0][n * 4 + 0] * invJ + IP_EPS;
      float d11 = red[0][n * 4 + 1] * invJ + IP_EPS;
      float d01r = red[0][n * 4 + 2] * invJ;
      float d01i = red[0][n * 4 + 3] * invJ;
      float A00r = w00r * d00 + (w01r * d01r + w01i * d01i);
      float A00i = w00i * d00 + (w01i * d01r - w01r * d01i);
      float A01r = (w00r * d01r - w00i * d01i) + w01r * d11;
      float A01i = (w00r * d01i + w00i * d01r) + w01i * d11;
      float A10r = w10r * d00 + (w11r * d01r + w11i * d01i);
      float A10i = w10i * d00 + (w11i * d01r - w11r * d01i);
      float A11r = (w10r * d01r - w10i * d01i) + w11r * d11;
      float A11i = (w10r * d01i + w10i * d01r) + w11i * d11;
      float detr = (A00r * A11r - A00i * A11i) - (A01r * A10r - A01i * A10i);
      float deti = (A00r * A11i + A00i * A11r) - (A01r * A10i + A01i * A10r);
      float idet = 1.0f / (detr * detr + deti * deti);
      float n0r, n0i, n1r, n1i;
      if (n == 0) { n0r = A11r; n0i = A11i; n1r = -A10r; n1i = -A10i; }
      else        { n0r = -A01r; n0i = -A01i; n1r = A00r; n1i = A00i; }
      float b0r = (n0r * detr + n0i * deti) * idet;
      float b0i = (n0i * detr - n0r * deti) * idet;
      float b1r = (n1r * detr + n1i * deti) * idet;
      float b1i = (n1i * detr - n1r * deti) * idet;
      float cr = d01r * b1r - d01i * b1i;
      float ci = d01r * b1i + d01i * b1r;
      float quad = d00 * (b0r * b0r + b0i * b0i) + d11 * (b1r * b1r + b1i * b1i)
                 + 2.0f * (b0r * cr + b0i * ci);
      float s = 1.0f / sqrtf(quad + IP_EPS);
      if (n == 0) { w00r = b0r * s; w00i = -b0i * s; w01r = b1r * s; w01i = -b1i * s; }
      else        { w10r = b0r * s; w10i = -b0i * s; w11r = b1r * s; w11i = -b1i * s; }
    }
    ((float4*)W)[i * 2]     = make_float4(w00r, w00i, w01r, w01i);
    ((float4*)W)[i * 2 + 1] = make_float4(w10r, w10i, w11r, w11i);
    wrow[0] = w00r; wrow[1] = w00i; wrow[2] = w01r; wrow[3] = w01i;
    wrow[4] = w10r; wrow[5] = w10i; wrow[6] = w11r; wrow[7] = w11i;
  }
  __syncthreads();
}

// ---- standalone kernels ----
template<int PK>
__global__ __launch_bounds__(256) void k_T(const __half* __restrict__ Xht,
                                           const float2* __restrict__ X,
                                           const float* __restrict__ W,
                                           float* __restrict__ T,
                                           const float* __restrict__ V) {
  __shared__ float Vl[16][CHJ];
  __shared__ float red[4][32];
  const int i = blockIdx.x;
  const float4 w0 = ((const float4*)W)[i * 2];
  const float4 w1 = ((const float4*)W)[i * 2 + 1];
  t_phase<PK>(i, Xht, X, w0, w1, T, V, Vl, red);
}

template<int PK>
__global__ __launch_bounds__(256) void k_D(const __half* __restrict__ Xht,
                                           const float2* __restrict__ X,
                                           const float* __restrict__ T,
                                           const float* __restrict__ V,
                                           float* __restrict__ W) {
  __shared__ float Vl[16][CHJ];
  __shared__ float red[4][32];
  __shared__ float wrow[8];
  d_phase<PK>(blockIdx.x, Xht, X, T, V, W, Vl, red, wrow);
}

// D of iter it fused with T of iter it+1 (same row; new W row via LDS)
template<int PK>
__global__ __launch_bounds__(256) void k_DT(const __half* __restrict__ Xht,
                                            const float2* __restrict__ X,
                                            float* __restrict__ T,
                                            const float* __restrict__ V,
                                            float* __restrict__ W) {
  __shared__ float Vl[16][CHJ];
  __shared__ float red[4][32];
  __shared__ float wrow[8];
  const int i = blockIdx.x;
  d_phase<PK>(i, Xht, X, T, V, W, Vl, red, wrow);
  const float4 w0 = make_float4(wrow[0], wrow[1], wrow[2], wrow[3]);
  const float4 w1 = make_float4(wrow[4], wrow[5], wrow[6], wrow[7]);
  __syncthreads();
  t_phase<PK>(i, Xht, X, w0, w1, T, V, Vl, red);
}

// ==== V update: block per j, threads stride i, reduce, in place ====
template<int PK>
__global__ __launch_bounds__(256) void k_V(const __half* __restrict__ Xhj,
                                           const float2* __restrict__ X,
                                           const float* __restrict__ W,
                                           const float* __restrict__ T,
                                           float* __restrict__ V) {
  const int j = blockIdx.x;
  const int tid = threadIdx.x;
  float vold0[K_B], vold1[K_B];
#pragma unroll
  for (int k = 0; k < K_B; ++k) {
    vold0[k] = V[(size_t)k * J_F + j];
    vold1[k] = V[(size_t)(K_B + k) * J_F + j];
  }
  float num0[K_B] = {}, den0[K_B] = {}, num1[K_B] = {}, den1[K_B] = {};
  const float* T1 = T + (size_t)I_F * K_B;
  const __half* xcol = Xhj + (size_t)j * I_F * 4;
  for (int i = tid; i < I_F; i += 256) {
    float4 x;
    if (PK) {
      uint2 raw = *(const uint2*)(xcol + (size_t)i * 4);
      x = h4f(raw.x, raw.y);
    } else {
      float2 a = X[(size_t)j * I_F + i];
      float2 c = X[(size_t)(J_F + j) * I_F + i];
      x = make_float4(a.x, a.y, c.x, c.y);
    }
    const float4 wa = ((const float4*)W)[i * 2];
    const float4 wb = ((const float4*)W)[i * 2 + 1];
    float yr = wa.x * x.x - wa.y * x.y + wa.z * x.z - wa.w * x.w;
    float yi = wa.x * x.y + wa.y * x.x + wa.z * x.w + wa.w * x.z;
    float p0 = yr * yr + yi * yi;
    float zr = wb.x * x.x - wb.y * x.y + wb.z * x.z - wb.w * x.w;
    float zi = wb.x * x.y + wb.y * x.x + wb.z * x.w + wb.w * x.z;
    float p1 = zr * zr + zi * zi;
    const float4 ta = *(const float4*)&T[i * 8];
    const float4 tb = *(const float4*)&T[i * 8 + 4];
    const float4 tc = *(const float4*)&T1[i * 8];
    const float4 td = *(const float4*)&T1[i * 8 + 4];
    float t0[K_B] = {ta.x, ta.y, ta.z, ta.w, tb.x, tb.y, tb.z, tb.w};
    float t1[K_B] = {tc.x, tc.y, tc.z, tc.w, td.x, td.y, td.z, td.w};
    float R0 = 0.f, R1 = 0.f;
#pragma unroll
    for (int k = 0; k < K_B; ++k) { R0 += t0[k] * vold0[k]; R1 += t1[k] * vold1[k]; }
    float a0 = p0 / (R0 * R0), b0 = 1.0f / R0;
    float a1 = p1 / (R1 * R1), b1 = 1.0f / R1;
#pragma unroll
    for (int k = 0; k < K_B; ++k) {
      num0[k] += a0 * t0[k]; den0[k] += b0 * t0[k];
      num1[k] += a1 * t1[k]; den1[k] += b1 * t1[k];
    }
  }
  __shared__ float red[4][32];
  const int lane = tid & 63, wid = tid >> 6;
#pragma unroll
  for (int k = 0; k < K_B; ++k) {
    float a0 = num0[k], b0 = den0[k], a1 = num1[k], b1 = den1[k];
#pragma unroll
    for (int off = 32; off > 0; off >>= 1) {
      a0 += __shfl_xor(a0, off, 64);
      b0 += __shfl_xor(b0, off, 64);
      a1 += __shfl_xor(a1, off, 64);
      b1 += __shfl_xor(b1, off, 64);
    }
    if (lane == 0) {
      red[wid][k] = a0; red[wid][8 + k] = b0;
      red[wid][16 + k] = a1; red[wid][24 + k] = b1;
    }
  }
  __syncthreads();
  if (tid < 32) red[0][tid] = red[0][tid] + red[1][tid] + red[2][tid] + red[3][tid];
  __syncthreads();
  if (tid < 16) {
    int n = tid >> 3, k = tid & 7;
    float nu = red[0][n * 16 + k];
    float de = red[0][n * 16 + 8 + k];
    size_t idx = ((size_t)n * K_B + k) * J_F + j;
    float vo = V[idx];
    V[idx] = fmaxf(vo * sqrtf(nu / de), NMF_EPS);
  }
}

// ---------------- final: fp16 Xhj ----------------
template<int PK>
__global__ __launch_bounds__(256) void k_final(const __half* __restrict__ Xhj,
                                               const float2* __restrict__ X,
                                               const float* __restrict__ W,
                                               float2* __restrict__ out) {
  const int i = blockIdx.x * 256 + threadIdx.x;
  if (i >= I_F) return;
  const float4 wa = ((const float4*)W)[i * 2];
  const float4 wb = ((const float4*)W)[i * 2 + 1];
  const int j0 = blockIdx.y * 8;
  const int jend = min(8, J_F - j0);
  for (int jj = 0; jj < jend; ++jj) {
    const int j = j0 + jj;
    float4 x;
    if (PK) {
      uint2 raw = *(const uint2*)(Xhj + ((size_t)j * I_F + i) * 4);
      x = h4f(raw.x, raw.y);
    } else {
      float2 a = X[(size_t)j * I_F + i];
      float2 c = X[(size_t)(J_F + j) * I_F + i];
      x = make_float4(a.x, a.y, c.x, c.y);
    }
    float y0r = wa.x * x.x - wa.y * x.y + wa.z * x.z - wa.w * x.w;
    float y0i = wa.x * x.y + wa.y * x.x + wa.z * x.w + wa.w * x.z;
    out[(size_t)j * I_F + i] = make_float2(y0r, y0i);
    float y1r = wb.x * x.x - wb.y * x.y + wb.z * x.z - wb.w * x.w;
    float y1i = wb.x * x.y + wb.y * x.x + wb.z * x.w + wb.w * x.z;
    out[(size_t)(J_F + j) * I_F + i] = make_float2(y1r, y1i);
  }
}

extern "C" void kernel_launch(void* const* d_in, const int* in_sizes, int n_in,
                              void* d_out, int out_size, void* d_ws, size_t ws_size,
                              hipStream_t stream) {
  const float2* X = (const float2*)d_in[0];
  const float* T0 = (const float*)d_in[1];
  const float* V0 = (const float*)d_in[2];
  float2* outp = (float2*)d_out;
  char* ws = (char*)d_ws;
  size_t off = 0;
  auto alloc = [&](size_t bytes) -> void* {
    void* p = ws + off;
    off = (off + bytes + 255) & ~(size_t)255;
    return p;
  };
  float* W = (float*)alloc((size_t)I_F * 8 * 4);
  float* T = (float*)alloc((size_t)2 * I_F * K_B * 4);
  float* V = (float*)alloc((size_t)2 * K_B * J_F * 4);
  const size_t xh_sz = (size_t)J_F * I_F * 8;  // 32.8 MB each
  __half* Xht = nullptr;
  __half* Xhj = nullptr;
  if (off + 2 * xh_sz + 512 <= ws_size) {
    Xht = (__half*)alloc(xh_sz);
    Xhj = (__half*)alloc(xh_sz);
  }
  const int NBS = NB_TILE + NB_INIT;

  if (Xht) {
    k_setup<1><<<NBS, 256, 0, stream>>>(X, T0, V0, T, V, W, Xht, Xhj);
    k_T<1><<<I_F, 256, 0, stream>>>(Xht, X, W, T, V);
    for (int it = 0; it < N_IT; ++it) {
      k_V<1><<<J_F, 256, 0, stream>>>(Xhj, X, W, T, V);
      if (it < N_IT - 1)
        k_DT<1><<<I_F, 256, 0, stream>>>(Xht, X, T, V, W);
      else
        k_D<1><<<I_F, 256, 0, stream>>>(Xht, X, T, V, W);
    }
    k_final<1><<<dim3(9, 250), 256, 0, stream>>>(Xhj, X, W, outp);
  } else {
    k_setup<0><<<NBS, 256, 0, stream>>>(X, T0, V0, T, V, W, nullptr, nullptr);
    k_T<0><<<I_F, 256, 0, stream>>>(nullptr, X, W, T, V);
    for (int it = 0; it < N_IT; ++it) {
      k_V<0><<<J_F, 256, 0, stream>>>(nullptr, X, W, T, V);
      if (it < N_IT - 1)
        k_DT<0><<<I_F, 256, 0, stream>>>(nullptr, X, T, V, W);
      else
        k_D<0><<<I_F, 256, 0, stream>>>(nullptr, X, T, V, W);
    }
    k_final<0><<<dim3(9, 250), 256, 0, stream>>>(nullptr, X, W, outp);
  }
}

// Round 19
// 421.644 us; speedup vs baseline: 1.3444x; 1.3444x over previous
//
#include <hip/hip_runtime.h>
#include <hip/hip_fp16.h>

#define M_CH 2
#define J_F 2000
#define I_F 2049
#define K_B 8
#define N_IT 5
#define NMF_EPS 1e-20f
#define IP_EPS 1e-20f

#define NB_TILE (65 * 63)
#define NB_INIT 128

__device__ __forceinline__ float2 h2f(unsigned u) {
  __half2 h = *reinterpret_cast<__half2*>(&u);
  return __half22float2(h);
}
__device__ __forceinline__ float4 h4f(unsigned lo, unsigned hi) {
  float2 a = h2f(lo), b = h2f(hi);
  return make_float4(a.x, a.y, b.x, b.y);
}
__device__ __forceinline__ unsigned f2h(float a, float b) {
  __half2 h = __floats2half2_rn(a, b);
  return *reinterpret_cast<unsigned*>(&h);
}

// ===== setup: X -> Xhj + Xht (fp16); init Tsoa[n][k][i], V[n][k][j], Vh, W =====
template<int PK>
__global__ __launch_bounds__(256) void k_setup(const float2* __restrict__ X,
                                               const float* __restrict__ T0,
                                               const float* __restrict__ V0,
                                               float* __restrict__ T,
                                               float* __restrict__ V,
                                               __half* __restrict__ Vh,
                                               float* __restrict__ W,
                                               __half* __restrict__ Xht,
                                               __half* __restrict__ Xhj) {
  int b = blockIdx.x;
  const int tid = threadIdx.x;
  if (b < NB_TILE) {
    if (!PK) return;
    __shared__ float4 Tl[32][33];
    const int i0 = (b % 65) * 32, j0 = (b / 65) * 32;
    const int la = tid & 31, su = tid >> 5;
#pragma unroll
    for (int p = 0; p < 4; ++p) {
      int jj = su + p * 8;
      int i = i0 + la, j = j0 + jj;
      if (i < I_F && j < J_F) {
        float2 a = X[(size_t)j * I_F + i];
        float2 c = X[(size_t)(J_F + j) * I_F + i];
        float4 x = make_float4(a.x, a.y, c.x, c.y);
        Tl[la][jj] = x;
        *(uint2*)(Xhj + ((size_t)j * I_F + i) * 4) =
            make_uint2(f2h(x.x, x.y), f2h(x.z, x.w));
      }
    }
    __syncthreads();
#pragma unroll
    for (int p = 0; p < 4; ++p) {
      int ii = su + p * 8;
      int i = i0 + ii, j = j0 + la;
      if (i < I_F && j < J_F) {
        float4 x = Tl[ii][la];
        *(uint2*)(Xht + ((size_t)i * J_F + j) * 4) =
            make_uint2(f2h(x.x, x.y), f2h(x.z, x.w));
      }
    }
    return;
  }
  b -= NB_TILE;
  int t = b * 256 + tid;
  const int stride = NB_INIT * 256;
  // Tsoa[n][k][i]
  for (int idx = t; idx < 2 * K_B * I_F; idx += stride) {
    int n = idx / (K_B * I_F);
    int r = idx % (K_B * I_F);
    int k = r / I_F, i = r % I_F;
    T[idx] = T0[(i * K_B + k) * M_CH + n];
  }
  for (int idx = t; idx < 2 * K_B * J_F; idx += stride) {
    int n = idx / (K_B * J_F);
    int r = idx % (K_B * J_F);
    int k = r / J_F, j = r % J_F;
    float v = V0[(k * J_F + j) * M_CH + n];
    V[idx] = v;
    Vh[idx] = __float2half(v);
  }
  for (int i = t; i < I_F; i += stride) {
    W[i * 8 + 0] = 1.f; W[i * 8 + 1] = 0.f; W[i * 8 + 2] = 0.f; W[i * 8 + 3] = 0.f;
    W[i * 8 + 4] = 0.f; W[i * 8 + 5] = 0.f; W[i * 8 + 6] = 1.f; W[i * 8 + 7] = 0.f;
  }
}

// ==== T phase: row i, j-pairs, fp16 V, reduce, update Tsoa ====
template<int PK>
__device__ __forceinline__ void t_phase(const int i, const __half* __restrict__ Xht,
                                        const float2* __restrict__ X,
                                        const float4 w0, const float4 w1,
                                        float* __restrict__ T,
                                        const float* __restrict__ V,
                                        const __half* __restrict__ Vh,
                                        float (*red)[32]) {
  const int tid = threadIdx.x;
  float tr0[K_B], tr1[K_B];
#pragma unroll
  for (int k = 0; k < K_B; ++k) {
    tr0[k] = T[(size_t)k * I_F + i];
    tr1[k] = T[(size_t)(K_B + k) * I_F + i];
  }
  float num0[K_B] = {}, den0[K_B] = {}, num1[K_B] = {}, den1[K_B] = {};
  if (PK) {
    for (int j2 = tid; j2 < J_F / 2; j2 += 256) {
      const int j = j2 * 2;
      uint4 raw = *(const uint4*)(Xht + ((size_t)i * J_F + j) * 4);
      float4 xa = h4f(raw.x, raw.y);
      float4 xb = h4f(raw.z, raw.w);
      float2 v0p[K_B], v1p[K_B];
      float R0a = 0.f, R0b = 0.f, R1a = 0.f, R1b = 0.f;
#pragma unroll
      for (int k = 0; k < K_B; ++k) {
        v0p[k] = h2f(*(const unsigned*)(Vh + (size_t)k * J_F + j));
        v1p[k] = h2f(*(const unsigned*)(Vh + (size_t)(K_B + k) * J_F + j));
        R0a += tr0[k] * v0p[k].x; R0b += tr0[k] * v0p[k].y;
        R1a += tr1[k] * v1p[k].x; R1b += tr1[k] * v1p[k].y;
      }
      float yr, yi;
      yr = w0.x * xa.x - w0.y * xa.y + w0.z * xa.z - w0.w * xa.w;
      yi = w0.x * xa.y + w0.y * xa.x + w0.z * xa.w + w0.w * xa.z;
      float p0a = yr * yr + yi * yi;
      yr = w1.x * xa.x - w1.y * xa.y + w1.z * xa.z - w1.w * xa.w;
      yi = w1.x * xa.y + w1.y * xa.x + w1.z * xa.w + w1.w * xa.z;
      float p1a = yr * yr + yi * yi;
      yr = w0.x * xb.x - w0.y * xb.y + w0.z * xb.z - w0.w * xb.w;
      yi = w0.x * xb.y + w0.y * xb.x + w0.z * xb.w + w0.w * xb.z;
      float p0b = yr * yr + yi * yi;
      yr = w1.x * xb.x - w1.y * xb.y + w1.z * xb.z - w1.w * xb.w;
      yi = w1.x * xb.y + w1.y * xb.x + w1.z * xb.w + w1.w * xb.z;
      float p1b = yr * yr + yi * yi;
      float a0a = p0a / (R0a * R0a), b0a = 1.f / R0a;
      float a1a = p1a / (R1a * R1a), b1a = 1.f / R1a;
      float a0b = p0b / (R0b * R0b), b0b = 1.f / R0b;
      float a1b = p1b / (R1b * R1b), b1b = 1.f / R1b;
#pragma unroll
      for (int k = 0; k < K_B; ++k) {
        num0[k] += a0a * v0p[k].x + a0b * v0p[k].y;
        den0[k] += b0a * v0p[k].x + b0b * v0p[k].y;
        num1[k] += a1a * v1p[k].x + a1b * v1p[k].y;
        den1[k] += b1a * v1p[k].x + b1b * v1p[k].y;
      }
    }
  } else {
    for (int j = tid; j < J_F; j += 256) {
      float2 a = X[(size_t)j * I_F + i];
      float2 c = X[(size_t)(J_F + j) * I_F + i];
      float4 x = make_float4(a.x, a.y, c.x, c.y);
      float yr = w0.x * x.x - w0.y * x.y + w0.z * x.z - w0.w * x.w;
      float yi = w0.x * x.y + w0.y * x.x + w0.z * x.w + w0.w * x.z;
      float p0 = yr * yr + yi * yi;
      float zr = w1.x * x.x - w1.y * x.y + w1.z * x.z - w1.w * x.w;
      float zi = w1.x * x.y + w1.y * x.x + w1.z * x.w + w1.w * x.z;
      float p1 = zr * zr + zi * zi;
      float v0[K_B], v1[K_B];
      float R0 = 0.f, R1 = 0.f;
#pragma unroll
      for (int k = 0; k < K_B; ++k) {
        v0[k] = V[(size_t)k * J_F + j];         R0 += tr0[k] * v0[k];
        v1[k] = V[(size_t)(K_B + k) * J_F + j]; R1 += tr1[k] * v1[k];
      }
      float a0 = p0 / (R0 * R0), b0 = 1.0f / R0;
      float a1 = p1 / (R1 * R1), b1 = 1.0f / R1;
#pragma unroll
      for (int k = 0; k < K_B; ++k) {
        num0[k] += a0 * v0[k]; den0[k] += b0 * v0[k];
        num1[k] += a1 * v1[k]; den1[k] += b1 * v1[k];
      }
    }
  }
  const int lane = tid & 63, wid = tid >> 6;
#pragma unroll
  for (int k = 0; k < K_B; ++k) {
    float a0 = num0[k], b0 = den0[k], a1 = num1[k], b1 = den1[k];
#pragma unroll
    for (int off = 32; off > 0; off >>= 1) {
      a0 += __shfl_xor(a0, off, 64);
      b0 += __shfl_xor(b0, off, 64);
      a1 += __shfl_xor(a1, off, 64);
      b1 += __shfl_xor(b1, off, 64);
    }
    if (lane == 0) {
      red[wid][k] = a0; red[wid][8 + k] = b0;
      red[wid][16 + k] = a1; red[wid][24 + k] = b1;
    }
  }
  __syncthreads();
  if (tid < 32) red[0][tid] = red[0][tid] + red[1][tid] + red[2][tid] + red[3][tid];
  __syncthreads();
  if (tid < 16) {
    int n = tid >> 3, k = tid & 7;
    float nu = red[0][n * 16 + k];
    float de = red[0][n * 16 + 8 + k];
    size_t idx = ((size_t)(n * K_B + k)) * I_F + i;
    float told = T[idx];
    T[idx] = fmaxf(told * sqrtf(nu / de), NMF_EPS);
  }
  __syncthreads();
}

// ==== D phase: row i, j-quads, fp16 V, reduce 8 sums, thread0 solves ====
template<int PK>
__device__ __forceinline__ void d_phase(const int i, const __half* __restrict__ Xht,
                                        const float2* __restrict__ X,
                                        const float* __restrict__ T,
                                        const float* __restrict__ V,
                                        const __half* __restrict__ Vh,
                                        float* __restrict__ W,
                                        float (*red)[32], float* wrow) {
  const int tid = threadIdx.x;
  float tr0[K_B], tr1[K_B];
#pragma unroll
  for (int k = 0; k < K_B; ++k) {
    tr0[k] = T[(size_t)k * I_F + i];
    tr1[k] = T[(size_t)(K_B + k) * I_F + i];
  }
  float acc[8] = {};
  if (PK) {
    for (int q = tid; q < J_F / 4; q += 256) {
      const int j = q * 4;
      uint4 ra = *(const uint4*)(Xht + ((size_t)i * J_F + j) * 4);
      uint4 rb = *(const uint4*)(Xht + ((size_t)i * J_F + j + 2) * 4);
      float4 xa = h4f(ra.x, ra.y);
      float4 xb = h4f(ra.z, ra.w);
      float4 xc = h4f(rb.x, rb.y);
      float4 xd = h4f(rb.z, rb.w);
      float R0a = 0.f, R0b = 0.f, R0c = 0.f, R0d = 0.f;
      float R1a = 0.f, R1b = 0.f, R1c = 0.f, R1d = 0.f;
#pragma unroll
      for (int k = 0; k < K_B; ++k) {
        uint2 u0 = *(const uint2*)(Vh + (size_t)k * J_F + j);
        uint2 u1 = *(const uint2*)(Vh + (size_t)(K_B + k) * J_F + j);
        float2 pa = h2f(u0.x), pb = h2f(u0.y);
        float2 qa = h2f(u1.x), qb = h2f(u1.y);
        R0a += tr0[k] * pa.x; R0b += tr0[k] * pa.y;
        R0c += tr0[k] * pb.x; R0d += tr0[k] * pb.y;
        R1a += tr1[k] * qa.x; R1b += tr1[k] * qa.y;
        R1c += tr1[k] * qb.x; R1d += tr1[k] * qb.y;
      }
      float wv0a = 1.0f / (R0a + IP_EPS), wv0b = 1.0f / (R0b + IP_EPS);
      float wv0c = 1.0f / (R0c + IP_EPS), wv0d = 1.0f / (R0d + IP_EPS);
      float wv1a = 1.0f / (R1a + IP_EPS), wv1b = 1.0f / (R1b + IP_EPS);
      float wv1c = 1.0f / (R1c + IP_EPS), wv1d = 1.0f / (R1d + IP_EPS);
      float p00a = xa.x * xa.x + xa.y * xa.y, p00b = xb.x * xb.x + xb.y * xb.y;
      float p00c = xc.x * xc.x + xc.y * xc.y, p00d = xd.x * xd.x + xd.y * xd.y;
      float p11a = xa.z * xa.z + xa.w * xa.w, p11b = xb.z * xb.z + xb.w * xb.w;
      float p11c = xc.z * xc.z + xc.w * xc.w, p11d = xd.z * xd.z + xd.w * xd.w;
      float pra = xa.x * xa.z + xa.y * xa.w, prb = xb.x * xb.z + xb.y * xb.w;
      float prc = xc.x * xc.z + xc.y * xc.w, prd = xd.x * xd.z + xd.y * xd.w;
      float pia = xa.y * xa.z - xa.x * xa.w, pib = xb.y * xb.z - xb.x * xb.w;
      float pic = xc.y * xc.z - xc.x * xc.w, pid = xd.y * xd.z - xd.x * xd.w;
      acc[0] += (wv0a * p00a + wv0b * p00b) + (wv0c * p00c + wv0d * p00d);
      acc[1] += (wv0a * p11a + wv0b * p11b) + (wv0c * p11c + wv0d * p11d);
      acc[2] += (wv0a * pra + wv0b * prb) + (wv0c * prc + wv0d * prd);
      acc[3] += (wv0a * pia + wv0b * pib) + (wv0c * pic + wv0d * pid);
      acc[4] += (wv1a * p00a + wv1b * p00b) + (wv1c * p00c + wv1d * p00d);
      acc[5] += (wv1a * p11a + wv1b * p11b) + (wv1c * p11c + wv1d * p11d);
      acc[6] += (wv1a * pra + wv1b * prb) + (wv1c * prc + wv1d * prd);
      acc[7] += (wv1a * pia + wv1b * pib) + (wv1c * pic + wv1d * pid);
    }
  } else {
    for (int j = tid; j < J_F; j += 256) {
      float2 a = X[(size_t)j * I_F + i];
      float2 c = X[(size_t)(J_F + j) * I_F + i];
      float4 x = make_float4(a.x, a.y, c.x, c.y);
      float R0 = 0.f, R1 = 0.f;
#pragma unroll
      for (int k = 0; k < K_B; ++k) {
        R0 += tr0[k] * V[(size_t)k * J_F + j];
        R1 += tr1[k] * V[(size_t)(K_B + k) * J_F + j];
      }
      float wv0 = 1.0f / (R0 + IP_EPS);
      float wv1 = 1.0f / (R1 + IP_EPS);
      float p00 = x.x * x.x + x.y * x.y;
      float p11 = x.z * x.z + x.w * x.w;
      float pr = x.x * x.z + x.y * x.w;
      float pi = x.y * x.z - x.x * x.w;
      acc[0] += wv0 * p00; acc[1] += wv0 * p11; acc[2] += wv0 * pr; acc[3] += wv0 * pi;
      acc[4] += wv1 * p00; acc[5] += wv1 * p11; acc[6] += wv1 * pr; acc[7] += wv1 * pi;
    }
  }
  const int lane = tid & 63, wid = tid >> 6;
#pragma unroll
  for (int v = 0; v < 8; ++v) {
    float a = acc[v];
#pragma unroll
    for (int off = 32; off > 0; off >>= 1) a += __shfl_xor(a, off, 64);
    if (lane == 0) red[wid][v] = a;
  }
  __syncthreads();
  if (tid < 8) red[0][tid] = red[0][tid] + red[1][tid] + red[2][tid] + red[3][tid];
  __syncthreads();
  if (tid == 0) {
    float4 wa = ((const float4*)W)[i * 2];
    float4 wb = ((const float4*)W)[i * 2 + 1];
    float w00r = wa.x, w00i = wa.y, w01r = wa.z, w01i = wa.w;
    float w10r = wb.x, w10i = wb.y, w11r = wb.z, w11i = wb.w;
    const float invJ = 1.0f / (float)J_F;
#pragma unroll
    for (int n = 0; n < 2; ++n) {
      float d00 = red[0][n * 4 + 0] * invJ + IP_EPS;
      float d11 = red[0][n * 4 + 1] * invJ + IP_EPS;
      float d01r = red[0][n * 4 + 2] * invJ;
      float d01i = red[0][n * 4 + 3] * invJ;
      float A00r = w00r * d00 + (w01r * d01r + w01i * d01i);
      float A00i = w00i * d00 + (w01i * d01r - w01r * d01i);
      float A01r = (w00r * d01r - w00i * d01i) + w01r * d11;
      float A01i = (w00r * d01i + w00i * d01r) + w01i * d11;
      float A10r = w10r * d00 + (w11r * d01r + w11i * d01i);
      float A10i = w10i * d00 + (w11i * d01r - w11r * d01i);
      float A11r = (w10r * d01r - w10i * d01i) + w11r * d11;
      float A11i = (w10r * d01i + w10i * d01r) + w11i * d11;
      float detr = (A00r * A11r - A00i * A11i) - (A01r * A10r - A01i * A10i);
      float deti = (A00r * A11i + A00i * A11r) - (A01r * A10i + A01i * A10r);
      float idet = 1.0f / (detr * detr + deti * deti);
      float n0r, n0i, n1r, n1i;
      if (n == 0) { n0r = A11r; n0i = A11i; n1r = -A10r; n1i = -A10i; }
      else        { n0r = -A01r; n0i = -A01i; n1r = A00r; n1i = A00i; }
      float b0r = (n0r * detr + n0i * deti) * idet;
      float b0i = (n0i * detr - n0r * deti) * idet;
      float b1r = (n1r * detr + n1i * deti) * idet;
      float b1i = (n1i * detr - n1r * deti) * idet;
      float cr = d01r * b1r - d01i * b1i;
      float ci = d01r * b1i + d01i * b1r;
      float quad = d00 * (b0r * b0r + b0i * b0i) + d11 * (b1r * b1r + b1i * b1i)
                 + 2.0f * (b0r * cr + b0i * ci);
      float s = 1.0f / sqrtf(quad + IP_EPS);
      if (n == 0) { w00r = b0r * s; w00i = -b0i * s; w01r = b1r * s; w01i = -b1i * s; }
      else        { w10r = b0r * s; w10i = -b0i * s; w11r = b1r * s; w11i = -b1i * s; }
    }
    ((float4*)W)[i * 2]     = make_float4(w00r, w00i, w01r, w01i);
    ((float4*)W)[i * 2 + 1] = make_float4(w10r, w10i, w11r, w11i);
    wrow[0] = w00r; wrow[1] = w00i; wrow[2] = w01r; wrow[3] = w01i;
    wrow[4] = w10r; wrow[5] = w10i; wrow[6] = w11r; wrow[7] = w11i;
  }
  __syncthreads();
}

// ---- standalone kernels ----
template<int PK>
__global__ __launch_bounds__(256) void k_T(const __half* __restrict__ Xht,
                                           const float2* __restrict__ X,
                                           const float* __restrict__ W,
                                           float* __restrict__ T,
                                           const float* __restrict__ V,
                                           const __half* __restrict__ Vh) {
  __shared__ float red[4][32];
  const int i = blockIdx.x;
  const float4 w0 = ((const float4*)W)[i * 2];
  const float4 w1 = ((const float4*)W)[i * 2 + 1];
  t_phase<PK>(i, Xht, X, w0, w1, T, V, Vh, red);
}

template<int PK>
__global__ __launch_bounds__(256) void k_D(const __half* __restrict__ Xht,
                                           const float2* __restrict__ X,
                                           const float* __restrict__ T,
                                           const float* __restrict__ V,
                                           const __half* __restrict__ Vh,
                                           float* __restrict__ W) {
  __shared__ float red[4][32];
  __shared__ float wrow[8];
  d_phase<PK>(blockIdx.x, Xht, X, T, V, Vh, W, red, wrow);
}

// D of iter it fused with T of iter it+1 (same row; new W row via LDS)
template<int PK>
__global__ __launch_bounds__(256) void k_DT(const __half* __restrict__ Xht,
                                            const float2* __restrict__ X,
                                            float* __restrict__ T,
                                            const float* __restrict__ V,
                                            const __half* __restrict__ Vh,
                                            float* __restrict__ W) {
  __shared__ float red[4][32];
  __shared__ float wrow[8];
  const int i = blockIdx.x;
  d_phase<PK>(i, Xht, X, T, V, Vh, W, red, wrow);
  const float4 w0 = make_float4(wrow[0], wrow[1], wrow[2], wrow[3]);
  const float4 w1 = make_float4(wrow[4], wrow[5], wrow[6], wrow[7]);
  __syncthreads();
  t_phase<PK>(i, Xht, X, w0, w1, T, V, Vh, red);
}

// ==== V update: block per j, threads stride i (coalesced SoA T), in place ====
template<int PK>
__global__ __launch_bounds__(256) void k_V(const __half* __restrict__ Xhj,
                                           const float2* __restrict__ X,
                                           const float* __restrict__ W,
                                           const float* __restrict__ T,
                                           float* __restrict__ V,
                                           __half* __restrict__ Vh) {
  const int j = blockIdx.x;
  const int tid = threadIdx.x;
  float vold0[K_B], vold1[K_B];
#pragma unroll
  for (int k = 0; k < K_B; ++k) {
    vold0[k] = V[(size_t)k * J_F + j];
    vold1[k] = V[(size_t)(K_B + k) * J_F + j];
  }
  float num0[K_B] = {}, den0[K_B] = {}, num1[K_B] = {}, den1[K_B] = {};
  const __half* xcol = Xhj + (size_t)j * I_F * 4;
  for (int i = tid; i < I_F; i += 256) {
    float4 x;
    if (PK) {
      uint2 raw = *(const uint2*)(xcol + (size_t)i * 4);
      x = h4f(raw.x, raw.y);
    } else {
      float2 a = X[(size_t)j * I_F + i];
      float2 c = X[(size_t)(J_F + j) * I_F + i];
      x = make_float4(a.x, a.y, c.x, c.y);
    }
    const float4 wa = ((const float4*)W)[i * 2];
    const float4 wb = ((const float4*)W)[i * 2 + 1];
    float yr = wa.x * x.x - wa.y * x.y + wa.z * x.z - wa.w * x.w;
    float yi = wa.x * x.y + wa.y * x.x + wa.z * x.w + wa.w * x.z;
    float p0 = yr * yr + yi * yi;
    float zr = wb.x * x.x - wb.y * x.y + wb.z * x.z - wb.w * x.w;
    float zi = wb.x * x.y + wb.y * x.x + wb.z * x.w + wb.w * x.z;
    float p1 = zr * zr + zi * zi;
    float t0[K_B], t1[K_B];
    float R0 = 0.f, R1 = 0.f;
#pragma unroll
    for (int k = 0; k < K_B; ++k) {
      t0[k] = T[(size_t)k * I_F + i];
      t1[k] = T[(size_t)(K_B + k) * I_F + i];
      R0 += t0[k] * vold0[k];
      R1 += t1[k] * vold1[k];
    }
    float a0 = p0 / (R0 * R0), b0 = 1.0f / R0;
    float a1 = p1 / (R1 * R1), b1 = 1.0f / R1;
#pragma unroll
    for (int k = 0; k < K_B; ++k) {
      num0[k] += a0 * t0[k]; den0[k] += b0 * t0[k];
      num1[k] += a1 * t1[k]; den1[k] += b1 * t1[k];
    }
  }
  __shared__ float red[4][32];
  const int lane = tid & 63, wid = tid >> 6;
#pragma unroll
  for (int k = 0; k < K_B; ++k) {
    float a0 = num0[k], b0 = den0[k], a1 = num1[k], b1 = den1[k];
#pragma unroll
    for (int off = 32; off > 0; off >>= 1) {
      a0 += __shfl_xor(a0, off, 64);
      b0 += __shfl_xor(b0, off, 64);
      a1 += __shfl_xor(a1, off, 64);
      b1 += __shfl_xor(b1, off, 64);
    }
    if (lane == 0) {
      red[wid][k] = a0; red[wid][8 + k] = b0;
      red[wid][16 + k] = a1; red[wid][24 + k] = b1;
    }
  }
  __syncthreads();
  if (tid < 32) red[0][tid] = red[0][tid] + red[1][tid] + red[2][tid] + red[3][tid];
  __syncthreads();
  if (tid < 16) {
    int n = tid >> 3, k = tid & 7;
    float nu = red[0][n * 16 + k];
    float de = red[0][n * 16 + 8 + k];
    size_t idx = ((size_t)(n * K_B + k)) * J_F + j;
    float vo = V[idx];
    float vn = fmaxf(vo * sqrtf(nu / de), NMF_EPS);
    V[idx] = vn;
    Vh[idx] = __float2half(vn);
  }
}

// ---------------- final: fp16 Xhj ----------------
template<int PK>
__global__ __launch_bounds__(256) void k_final(const __half* __restrict__ Xhj,
                                               const float2* __restrict__ X,
                                               const float* __restrict__ W,
                                               float2* __restrict__ out) {
  const int i = blockIdx.x * 256 + threadIdx.x;
  if (i >= I_F) return;
  const float4 wa = ((const float4*)W)[i * 2];
  const float4 wb = ((const float4*)W)[i * 2 + 1];
  const int j0 = blockIdx.y * 8;
  const int jend = min(8, J_F - j0);
  for (int jj = 0; jj < jend; ++jj) {
    const int j = j0 + jj;
    float4 x;
    if (PK) {
      uint2 raw = *(const uint2*)(Xhj + ((size_t)j * I_F + i) * 4);
      x = h4f(raw.x, raw.y);
    } else {
      float2 a = X[(size_t)j * I_F + i];
      float2 c = X[(size_t)(J_F + j) * I_F + i];
      x = make_float4(a.x, a.y, c.x, c.y);
    }
    float y0r = wa.x * x.x - wa.y * x.y + wa.z * x.z - wa.w * x.w;
    float y0i = wa.x * x.y + wa.y * x.x + wa.z * x.w + wa.w * x.z;
    out[(size_t)j * I_F + i] = make_float2(y0r, y0i);
    float y1r = wb.x * x.x - wb.y * x.y + wb.z * x.z - wb.w * x.w;
    float y1i = wb.x * x.y + wb.y * x.x + wb.z * x.w + wb.w * x.z;
    out[(size_t)(J_F + j) * I_F + i] = make_float2(y1r, y1i);
  }
}

extern "C" void kernel_launch(void* const* d_in, const int* in_sizes, int n_in,
                              void* d_out, int out_size, void* d_ws, size_t ws_size,
                              hipStream_t stream) {
  const float2* X = (const float2*)d_in[0];
  const float* T0 = (const float*)d_in[1];
  const float* V0 = (const float*)d_in[2];
  float2* outp = (float2*)d_out;
  char* ws = (char*)d_ws;
  size_t off = 0;
  auto alloc = [&](size_t bytes) -> void* {
    void* p = ws + off;
    off = (off + bytes + 255) & ~(size_t)255;
    return p;
  };
  float* W = (float*)alloc((size_t)I_F * 8 * 4);
  float* T = (float*)alloc((size_t)2 * K_B * I_F * 4);
  float* V = (float*)alloc((size_t)2 * K_B * J_F * 4);
  __half* Vh = (__half*)alloc((size_t)2 * K_B * J_F * 2);
  const size_t xh_sz = (size_t)J_F * I_F * 8;  // 32.8 MB each
  __half* Xht = nullptr;
  __half* Xhj = nullptr;
  if (off + 2 * xh_sz + 512 <= ws_size) {
    Xht = (__half*)alloc(xh_sz);
    Xhj = (__half*)alloc(xh_sz);
  }
  const int NBS = NB_TILE + NB_INIT;

  if (Xht) {
    k_setup<1><<<NBS, 256, 0, stream>>>(X, T0, V0, T, V, Vh, W, Xht, Xhj);
    k_T<1><<<I_F, 256, 0, stream>>>(Xht, X, W, T, V, Vh);
    for (int it = 0; it < N_IT; ++it) {
      k_V<1><<<J_F, 256, 0, stream>>>(Xhj, X, W, T, V, Vh);
      if (it < N_IT - 1)
        k_DT<1><<<I_F, 256, 0, stream>>>(Xht, X, T, V, Vh, W);
      else
        k_D<1><<<I_F, 256, 0, stream>>>(Xht, X, T, V, Vh, W);
    }
    k_final<1><<<dim3(9, 250), 256, 0, stream>>>(Xhj, X, W, outp);
  } else {
    k_setup<0><<<NBS, 256, 0, stream>>>(X, T0, V0, T, V, Vh, W, nullptr, nullptr);
    k_T<0><<<I_F, 256, 0, stream>>>(nullptr, X, W, T, V, Vh);
    for (int it = 0; it < N_IT; ++it) {
      k_V<0><<<J_F, 256, 0, stream>>>(nullptr, X, W, T, V, Vh);
      if (it < N_IT - 1)
        k_DT<0><<<I_F, 256, 0, stream>>>(nullptr, X, T, V, Vh, W);
      else
        k_D<0><<<I_F, 256, 0, stream>>>(nullptr, X, T, V, Vh, W);
    }
    k_final<0><<<dim3(9, 250), 256, 0, stream>>>(nullptr, X, W, outp);
  }
}